// Round 6
// baseline (232.100 us; speedup 1.0000x reference)
//
#include <hip/hip_runtime.h>
#include <hip/hip_bf16.h>
#include <hip/hip_fp16.h>

#define SEQ 2048
#define DH  64
#define NH  16
#define DE  1024   // NH*DH

typedef float    f32x4  __attribute__((ext_vector_type(4)));
typedef float    fvec4  __attribute__((ext_vector_type(4)));
typedef __bf16   bf16x8 __attribute__((ext_vector_type(8)));
typedef _Float16 half8  __attribute__((ext_vector_type(8)));
typedef _Float16 f16x4  __attribute__((ext_vector_type(4)));

#define MFMA_BF16_K32(A,B,C) __builtin_amdgcn_mfma_f32_16x16x32_bf16(A,B,C,0,0,0)
#define MFMA_F16_K32(A,B,C)  __builtin_amdgcn_mfma_f32_16x16x32_f16(A,B,C,0,0,0)
#define MFMA_F16_K16(A,B,C)  __builtin_amdgcn_mfma_f32_16x16x16f16(A,B,C,0,0,0)

// async 16B global -> LDS (dst = wave-uniform base + lane*16)
__device__ __forceinline__ void gll16(void* lds, const void* g) {
    __builtin_amdgcn_global_load_lds(
        (const __attribute__((address_space(1))) unsigned int*)g,
        (__attribute__((address_space(3))) unsigned int*)lds, 16, 0, 0);
}

// ---------------------------------------------------------------------------
// One-shot f32 -> bf16 prep: xb, wqb, wkb(*0.125), wvb, wotb(transposed WO).
// ---------------------------------------------------------------------------
__global__ __launch_bounds__(256) void conv_all(
    const float* __restrict__ x,  const float* __restrict__ Wq,
    const float* __restrict__ Wk, const float* __restrict__ Wv,
    const float* __restrict__ Wo, __bf16* __restrict__ xb,
    __bf16* __restrict__ wqb, __bf16* __restrict__ wkb,
    __bf16* __restrict__ wvb, __bf16* __restrict__ wotb)
{
    long i = ((long)blockIdx.x * 256 + threadIdx.x) * 8;
    const float* src; __bf16* dst; float sc = 1.0f; long j;
    if (i < 2097152)      { j = i;            src = x  + j; dst = xb  + j; }
    else if (i < 3145728) { j = i - 2097152;  src = Wq + j; dst = wqb + j; }
    else if (i < 4194304) { j = i - 3145728;  src = Wk + j; dst = wkb + j; sc = 0.125f; }
    else if (i < 5242880) { j = i - 4194304;  src = Wv + j; dst = wvb + j; }
    else                  { j = i - 5242880;  src = Wo + j;
                            long a = j >> 16, e = (j >> 6) & 1023, h = j & 63;
                            dst = wotb + e * DE + a * 64 + h; }
    fvec4 u = *(const fvec4*)src;
    fvec4 w = *(const fvec4*)(src + 4);
    bf16x8 o;
    o[0]=(__bf16)(u.x*sc); o[1]=(__bf16)(u.y*sc); o[2]=(__bf16)(u.z*sc); o[3]=(__bf16)(u.w*sc);
    o[4]=(__bf16)(w.x*sc); o[5]=(__bf16)(w.y*sc); o[6]=(__bf16)(w.z*sc); o[7]=(__bf16)(w.w*sc);
    *(bf16x8*)dst = o;
}

// ---------------------------------------------------------------------------
// m97-density GEMM: C[m,n] = sum_k A[m,k]*B[n,k], bf16 in, BK=64,
// 256 thr = 4 waves, each wave owns quadrant (BM/2 x BN/2).
// global_load_lds(16B) staging with source-side XOR swizzle: LDS slot
// (row, p) holds global chunk p^(row&7); readers XOR identically ->
// b128 fragment reads hit the 8-phase structural floor (no extra phases).
// MODE 0 (BM=128,BN=128): fused QKV, N=3072: zi=base>>10 -> q/k f16
//   [a][c][h], v^T f16 [a][h][c].  MODE 1: f32 row-major (out projection).
// ---------------------------------------------------------------------------
template<int BM, int BN, int MODE>
__global__ __launch_bounds__(256) void gemm_t(
    const __bf16* __restrict__ A, const __bf16* __restrict__ B,
    __half* __restrict__ Cqk, __half* __restrict__ Cv, float* __restrict__ Cf)
{
    constexpr int MT = BM / 32;          // m 16-tiles per wave
    constexpr int NT = BN / 32;          // n 16-tiles per wave
    constexpr int NCH = (BM + BN) / 32;  // gll16 per thread per k-iter

    __shared__ __bf16 As[BM][64];
    __shared__ __bf16 Bs[BN][64];

    const int t = threadIdx.x, wave = t >> 6, lane = t & 63;
    const int bm = blockIdx.y * BM, bn = blockIdx.x * BN;
    const int il = lane & 15, q4 = lane >> 4;
    const int wm = (wave & 1) * (BM / 2), wn = (wave >> 1) * (BN / 2);

    f32x4 acc[MT][NT];
    #pragma unroll
    for (int i = 0; i < MT; ++i)
        #pragma unroll
        for (int j = 0; j < NT; ++j) acc[i][j] = (f32x4){0.f,0.f,0.f,0.f};

    for (int k0 = 0; k0 < DE; k0 += 64) {
        __syncthreads();
        #pragma unroll
        for (int i = 0; i < NCH; ++i) {
            int s = i * 256 + t;
            int row = s >> 3, ch = (s & 7) ^ (row & 7);
            if (s < BM * 8)
                gll16((__bf16*)As + (long)s * 8,
                      A + (long)(bm + row) * DE + k0 + ch * 8);
            else
                gll16((__bf16*)Bs + (long)(s - BM * 8) * 8,
                      B + (long)(bn + row - BM) * DE + k0 + ch * 8);
        }
        __syncthreads();
        #pragma unroll
        for (int kc = 0; kc < 2; ++kc) {
            bf16x8 af[MT], bff[NT];
            #pragma unroll
            for (int mt = 0; mt < MT; ++mt) {
                int row = wm + mt*16 + il, ch = (kc*4 + q4) ^ (row & 7);
                af[mt] = *(const bf16x8*)&As[row][ch * 8];
            }
            #pragma unroll
            for (int nt = 0; nt < NT; ++nt) {
                int row = wn + nt*16 + il, ch = (kc*4 + q4) ^ (row & 7);
                bff[nt] = *(const bf16x8*)&Bs[row][ch * 8];
            }
            #pragma unroll
            for (int mt = 0; mt < MT; ++mt)
                #pragma unroll
                for (int nt = 0; nt < NT; ++nt)
                    acc[mt][nt] = MFMA_BF16_K32(af[mt], bff[nt], acc[mt][nt]);
        }
    }

    #pragma unroll
    for (int mt = 0; mt < MT; ++mt) {
        const int m0 = bm + wm + mt*16 + q4*4;
        #pragma unroll
        for (int nt = 0; nt < NT; ++nt) {
            if (MODE == 0) {
                const int base = bn + wn + nt*16;        // uniform per nt
                const int zi   = base >> 10;             // 0=q 1=k 2=v
                const int head = (base >> 6) & 15;
                const int hb   = base & 63;
                #pragma unroll
                for (int r = 0; r < 4; ++r) {
                    float v = acc[mt][nt][r];
                    if (zi == 2)
                        Cv[(long)head*131072 + (long)(hb + il)*2048 + (m0 + r)] =
                            (__half)v;
                    else
                        Cqk[(long)zi*2097152 + (long)head*131072 +
                            (long)(m0 + r)*64 + hb + il] = (__half)v;
                }
            } else {
                const int n = bn + wn + nt*16 + il;
                #pragma unroll
                for (int r = 0; r < 4; ++r)
                    Cf[(long)(m0 + r) * DE + n] = acc[mt][nt][r];
            }
        }
    }
}

// ---------------------------------------------------------------------------
// Transposed-S MFMA flash attention, register-only K-loop, depth-2 prefetch.
// Reference roles: s[c,C]=k_c·q_C/8 (K pre-scaled), causal C<=c.
// Grid (NH, 64): jt = by<32 ? 63-by : by-32  — provably balanced: CU c gets
// blocks with jt sum == 126 for every c (4 blocks/CU, 8-wave blocks).
// Block covers 32-row c-tile: wsub=wave&1 -> 16-row strip, qtr=wave>>2... 
// qtr=wave>>1 -> quarter of the strip's C-chunk range (16-col granularity).
// Strip chunk count M = 2*jt + wsub + 1; chunk M-1 is the diagonal.
// Split-C partials combine by plain addition (no max-subtraction: |s|<=~8).
// T = MFMA(A=Q-frag,B=K-frag) = Sᵀ; its per-lane C/D layout equals the
// A-frag layout of mfma 16x16x16 f16, so exp(T) feeds PV directly (no LDS).
// Rowsum via ones-B MFMA (C/D layout == O layout -> elementwise divide).
// ---------------------------------------------------------------------------
__global__ __launch_bounds__(512, 4) void attn_mfma(
    const __half* __restrict__ Qh, const __half* __restrict__ Kh,
    const __half* __restrict__ Vt, __bf16* __restrict__ Z)
{
    __shared__ float smc[3][2][64][20];   // 30720 B combine buffer

    const int a    = blockIdx.x;
    const int by   = blockIdx.y;
    const int jt   = (by < 32) ? 63 - by : by - 32;   // balanced pairing
    const int t    = threadIdx.x;
    const int wave = t >> 6;
    const int lane = t & 63;
    const int qtr  = wave >> 1;          // C-range quarter 0..3
    const int wsub = wave & 1;           // 16-row strip within 32-row tile
    const int c0   = jt * 32;
    const int il   = lane & 15;
    const int q4   = lane >> 4;

    const int M    = 2*jt + wsub + 1;          // chunks for this strip
    const int mbeg = (qtr * M) >> 2;
    const int mend = ((qtr + 1) * M) >> 2;     // quarter 3 owns diag (M-1)

    const __half* qrow = Qh + ((long)a*SEQ + il)*DH + q4*8;
    const __half* vrow = Vt + (long)a*DH*SEQ + (long)il*SEQ + q4*4;

    // K B-fragments: fixed c-rows for this strip
    const __half* kp = Kh + ((long)a*SEQ + c0 + wsub*16 + il)*DH + q4*8;
    half8 kf0 = *(const half8*)(kp);
    half8 kf1 = *(const half8*)(kp + 32);

    f16x4 ones;
    #pragma unroll
    for (int j = 0; j < 4; ++j) ones[j] = (_Float16)1.0f;

    f32x4 o[4];
    #pragma unroll
    for (int ht = 0; ht < 4; ++ht) o[ht] = (f32x4){0.f,0.f,0.f,0.f};
    f32x4 lacc = {0.f,0.f,0.f,0.f};

    if (mbeg < mend) {
        half8 qa0, qb0, qa1, qb1, qa2, qb2;
        f16x4 va0[4], va1[4], va2[4];

        auto LQ = [&](int m, half8& A, half8& B) {
            const __half* p = qrow + (long)m * (16 * DH);
            A = *(const half8*)p;
            B = *(const half8*)(p + 32);
        };
        auto LV = [&](int m, f16x4 V[4]) {
            #pragma unroll
            for (int ht = 0; ht < 4; ++ht)
                V[ht] = *(const f16x4*)(vrow + (long)ht*16*SEQ + m*16);
        };

        LQ(mbeg, qa0, qb0); LV(mbeg, va0);
        const int m1 = (mbeg + 1 < mend) ? mbeg + 1 : mbeg;
        LQ(m1, qa1, qb1); LV(m1, va1);

        for (int m = mbeg; m < mend; ++m) {
            const int mn = (m + 2 < mend) ? m + 2 : mend - 1;
            LQ(mn, qa2, qb2); LV(mn, va2);    // depth-2 prefetch

            f32x4 T = {0.f,0.f,0.f,0.f};
            T = MFMA_F16_K32(qa0, kf0, T);
            T = MFMA_F16_K32(qb0, kf1, T);
            if (m == M - 1) {                 // diagonal chunk: mask C > c
                #pragma unroll
                for (int r = 0; r < 4; ++r)
                    if (q4*4 + r > il) T[r] = -1e30f;
            }
            f16x4 pf;
            #pragma unroll
            for (int r = 0; r < 4; ++r) pf[r] = (_Float16)__expf(T[r]);
            lacc = MFMA_F16_K16(pf, ones, lacc);
            #pragma unroll
            for (int ht = 0; ht < 4; ++ht)
                o[ht] = MFMA_F16_K16(pf, va0[ht], o[ht]);

            qa0 = qa1; qb0 = qb1;
            qa1 = qa2; qb1 = qb2;
            #pragma unroll
            for (int ht = 0; ht < 4; ++ht) { va0[ht] = va1[ht]; va1[ht] = va2[ht]; }
        }
    }

    // ---- combine quarters via LDS (stride 20 floats: 8-phase optimal b128)
    __syncthreads();
    if (qtr) {
        float* p = &smc[qtr - 1][wsub][lane][0];
        #pragma unroll
        for (int ht = 0; ht < 4; ++ht) *(f32x4*)(p + ht*4) = o[ht];
        *(f32x4*)(p + 16) = lacc;
    }
    __syncthreads();
    if (qtr == 0) {
        #pragma unroll
        for (int pq = 0; pq < 3; ++pq) {
            const float* p = &smc[pq][wsub][lane][0];
            #pragma unroll
            for (int ht = 0; ht < 4; ++ht) o[ht] += *(const f32x4*)(p + ht*4);
            lacc += *(const f32x4*)(p + 16);
        }
        float inv[4];
        #pragma unroll
        for (int r = 0; r < 4; ++r) inv[r] = 1.0f / lacc[r];
        // O C/D layout: row (c-local) = q4*4+r, col (h-local) = ht*16+il
        #pragma unroll
        for (int ht = 0; ht < 4; ++ht)
            #pragma unroll
            for (int r = 0; r < 4; ++r) {
                long row = c0 + wsub*16 + q4*4 + r;
                Z[row * DE + a*64 + ht*16 + il] = (__bf16)(o[ht][r] * inv[r]);
            }
    }
}

// ---------------------------------------------------------------------------
extern "C" void kernel_launch(void* const* d_in, const int* in_sizes, int n_in,
                              void* d_out, int out_size, void* d_ws, size_t ws_size,
                              hipStream_t stream)
{
    const float* x  = (const float*)d_in[0];
    const float* Wq = (const float*)d_in[1];
    const float* Wk = (const float*)d_in[2];
    const float* Wv = (const float*)d_in[3];
    const float* Wo = (const float*)d_in[4];
    float* out = (float*)d_out;

    const long M1 = 1024 * 1024;
    __bf16* wsb  = (__bf16*)d_ws;              // 14M 2B elems = 28 MB
    __bf16* xb   = wsb;                        // [c][e]        2M bf16
    __bf16* wqb  = wsb + 2*M1;                 // [a*64+h][e]   1M bf16
    __bf16* wkb  = wsb + 3*M1;                 // (pre-scaled 0.125)
    __bf16* wvb  = wsb + 4*M1;
    __bf16* wotb = wsb + 5*M1;                 // [e][a*64+h]   1M bf16
    __half* qkh  = (__half*)(wsb + 6*M1);      // q then k: [a][c][h] f16, 4M
    __half* vth  = (__half*)(wsb + 10*M1);     // [a][h][c] f16  2M
    __bf16* zb   = wsb + 12*M1;                // [c][a*64+h] bf16 2M
    (void)wkb; (void)wvb;

    conv_all<<<3072, 256, 0, stream>>>(x, Wq, Wk, Wv, Wo,
                                       xb, wqb, wkb, wvb, wotb);

    // fused QKV: B = [wq|wk|wv] (3072 x 1024) -> q/k f16 + v^T f16
    gemm_t<128,128,0><<<dim3(24, 16), 256, 0, stream>>>(xb, wqb, qkh, vth, nullptr);

    attn_mfma<<<dim3(NH, 64), 512, 0, stream>>>(qkh, qkh + 2*M1, vth, zb);

    // output projection: out = Z · WoT^T (f32 out)
    gemm_t<64,128,1><<<dim3(8, 32), 256, 0, stream>>>(zb, wotb, nullptr, nullptr, out);
}

// Round 8
// 145.693 us; speedup vs baseline: 1.5931x; 1.5931x over previous
//
#include <hip/hip_runtime.h>
#include <hip/hip_bf16.h>
#include <hip/hip_fp16.h>

#define SEQ 2048
#define DH  64
#define NH  16
#define DE  1024   // NH*DH

typedef float    f32x4  __attribute__((ext_vector_type(4)));
typedef float    fvec4  __attribute__((ext_vector_type(4)));
typedef __bf16   bf16x8 __attribute__((ext_vector_type(8)));
typedef _Float16 half8  __attribute__((ext_vector_type(8)));
typedef _Float16 f16x4  __attribute__((ext_vector_type(4)));

#define MFMA_BF16_K32(A,B,C) __builtin_amdgcn_mfma_f32_16x16x32_bf16(A,B,C,0,0,0)
#define MFMA_F16_K32(A,B,C)  __builtin_amdgcn_mfma_f32_16x16x32_f16(A,B,C,0,0,0)
#define MFMA_F16_K16(A,B,C)  __builtin_amdgcn_mfma_f32_16x16x16f16(A,B,C,0,0,0)

// async 16B global -> LDS (dst = wave-uniform base + lane*16)
__device__ __forceinline__ void gll16(void* lds, const void* g) {
    __builtin_amdgcn_global_load_lds(
        (const __attribute__((address_space(1))) unsigned int*)g,
        (__attribute__((address_space(3))) unsigned int*)lds, 16, 0, 0);
}

// ---------------------------------------------------------------------------
// One-shot f32 -> bf16 prep: xb, wqb, wkb(*0.125), wvb, wotb(transposed WO).
// ---------------------------------------------------------------------------
__global__ __launch_bounds__(256) void conv_all(
    const float* __restrict__ x,  const float* __restrict__ Wq,
    const float* __restrict__ Wk, const float* __restrict__ Wv,
    const float* __restrict__ Wo, __bf16* __restrict__ xb,
    __bf16* __restrict__ wqb, __bf16* __restrict__ wkb,
    __bf16* __restrict__ wvb, __bf16* __restrict__ wotb)
{
    long i = ((long)blockIdx.x * 256 + threadIdx.x) * 8;
    const float* src; __bf16* dst; float sc = 1.0f; long j;
    if (i < 2097152)      { j = i;            src = x  + j; dst = xb  + j; }
    else if (i < 3145728) { j = i - 2097152;  src = Wq + j; dst = wqb + j; }
    else if (i < 4194304) { j = i - 3145728;  src = Wk + j; dst = wkb + j; sc = 0.125f; }
    else if (i < 5242880) { j = i - 4194304;  src = Wv + j; dst = wvb + j; }
    else                  { j = i - 5242880;  src = Wo + j;
                            long a = j >> 16, e = (j >> 6) & 1023, h = j & 63;
                            dst = wotb + e * DE + a * 64 + h; }
    fvec4 u = *(const fvec4*)src;
    fvec4 w = *(const fvec4*)(src + 4);
    bf16x8 o;
    o[0]=(__bf16)(u.x*sc); o[1]=(__bf16)(u.y*sc); o[2]=(__bf16)(u.z*sc); o[3]=(__bf16)(u.w*sc);
    o[4]=(__bf16)(w.x*sc); o[5]=(__bf16)(w.y*sc); o[6]=(__bf16)(w.z*sc); o[7]=(__bf16)(w.w*sc);
    *(bf16x8*)dst = o;
}

// ---------------------------------------------------------------------------
// m97-density GEMM: C[m,n] = sum_k A[m,k]*B[n,k], bf16 in, BK=64,
// 256 thr = 4 waves, wave quadrant (BM/2 x BN/2), source-XOR-swizzled
// global_load_lds staging (conflict-free b128 fragment reads).
// MODE 0 (128x128, fused QKV N=3072): zi = bn>>10: q/k -> [a][c][h] f16
//   (head computed PER 16-col TILE: a 128-col block spans 2 heads — the R7
//   hoisted-head bug); v -> Vt [a][h][c] f16 via LDS transpose epilogue +
//   b128 coalesced stores.
// MODE 1: f32 row-major out (output projection).
// ---------------------------------------------------------------------------
template<int BM, int BN, int MODE>
__global__ __launch_bounds__(256) void gemm_t(
    const __bf16* __restrict__ A, const __bf16* __restrict__ B,
    __half* __restrict__ Cqk, __half* __restrict__ Cv, float* __restrict__ Cf)
{
    constexpr int MT = BM / 32;
    constexpr int NT = BN / 32;
    constexpr int NCH = (BM + BN) / 32;

    union SM {
        struct { __bf16 As[BM][64]; __bf16 Bs[BN][64]; } st;  // stage
        _Float16 tr[2][64][136];                               // V transpose
    };
    __shared__ __align__(16) SM sm;

    const int t = threadIdx.x, wave = t >> 6, lane = t & 63;
    const int bm = blockIdx.y * BM, bn = blockIdx.x * BN;
    const int il = lane & 15, q4 = lane >> 4;
    const int wm = (wave & 1) * (BM / 2), wn = (wave >> 1) * (BN / 2);

    f32x4 acc[MT][NT];
    #pragma unroll
    for (int i = 0; i < MT; ++i)
        #pragma unroll
        for (int j = 0; j < NT; ++j) acc[i][j] = (f32x4){0.f,0.f,0.f,0.f};

    for (int k0 = 0; k0 < DE; k0 += 64) {
        __syncthreads();
        #pragma unroll
        for (int i = 0; i < NCH; ++i) {
            int s = i * 256 + t;
            int row = s >> 3, ch = (s & 7) ^ (row & 7);
            if (s < BM * 8)
                gll16((__bf16*)sm.st.As + (long)s * 8,
                      A + (long)(bm + row) * DE + k0 + ch * 8);
            else
                gll16((__bf16*)sm.st.Bs + (long)(s - BM * 8) * 8,
                      B + (long)(bn + row - BM) * DE + k0 + ch * 8);
        }
        __syncthreads();
        #pragma unroll
        for (int kc = 0; kc < 2; ++kc) {
            bf16x8 af[MT], bff[NT];
            #pragma unroll
            for (int mt = 0; mt < MT; ++mt) {
                int row = wm + mt*16 + il, ch = (kc*4 + q4) ^ (row & 7);
                af[mt] = *(const bf16x8*)&sm.st.As[row][ch * 8];
            }
            #pragma unroll
            for (int nt = 0; nt < NT; ++nt) {
                int row = wn + nt*16 + il, ch = (kc*4 + q4) ^ (row & 7);
                bff[nt] = *(const bf16x8*)&sm.st.Bs[row][ch * 8];
            }
            #pragma unroll
            for (int mt = 0; mt < MT; ++mt)
                #pragma unroll
                for (int nt = 0; nt < NT; ++nt)
                    acc[mt][nt] = MFMA_BF16_K32(af[mt], bff[nt], acc[mt][nt]);
        }
    }

    if (MODE == 0) {
        const int zi = bn >> 10;            // 0=q 1=k 2=v (uniform per block)
        if (zi == 2) {
            // ---- transpose epilogue: acc[c][h] -> Vt[head][h][c]
            __syncthreads();                 // staging reads done
            const int hh = wn >> 6;          // head-half within 128 cols
            #pragma unroll
            for (int mt = 0; mt < MT; ++mt) {
                const int ml = wm + mt*16 + q4*4;
                #pragma unroll
                for (int nt = 0; nt < NT; ++nt) {
                    const int hl = (wn & 63) + nt*16 + il;
                    f16x4 v4;
                    #pragma unroll
                    for (int r = 0; r < 4; ++r) v4[r] = (_Float16)acc[mt][nt][r];
                    *(f16x4*)&sm.tr[hh][hl][ml] = v4;
                }
            }
            __syncthreads();
            const int hbase = (bn & 1023) >> 6;          // 0,2,...,14
            #pragma unroll
            for (int i = 0; i < 8; ++i) {
                int s = i*256 + t;
                int hh2 = s >> 10, rem = s & 1023, hl = rem >> 4, ch = rem & 15;
                half8 val = *(const half8*)&sm.tr[hh2][hl][ch*8];
                *(half8*)&Cv[(long)(hbase + hh2)*131072 + (long)hl*2048 + bm + ch*8] = val;
            }
        } else {
            #pragma unroll
            for (int mt = 0; mt < MT; ++mt) {
                const int m0 = bm + wm + mt*16 + q4*4;
                #pragma unroll
                for (int nt = 0; nt < NT; ++nt) {
                    const int base = bn + wn + nt*16;    // 16-col tile origin
                    const int head = (base >> 6) & 15;   // per-tile head (FIX)
                    const int hb   = base & 63;
                    #pragma unroll
                    for (int r = 0; r < 4; ++r)
                        Cqk[(long)zi*2097152 + (long)head*131072 +
                            (long)(m0 + r)*64 + hb + il] = (__half)acc[mt][nt][r];
                }
            }
        }
    } else {
        #pragma unroll
        for (int mt = 0; mt < MT; ++mt) {
            const int m0 = bm + wm + mt*16 + q4*4;
            #pragma unroll
            for (int nt = 0; nt < NT; ++nt) {
                const int n = bn + wn + nt*16 + il;
                #pragma unroll
                for (int r = 0; r < 4; ++r)
                    Cf[(long)(m0 + r) * DE + n] = acc[mt][nt][r];
            }
        }
    }
}

// ---------------------------------------------------------------------------
// LDS-staged MFMA flash attention (reference roles: s[c,C]=k_c.q_C/8, C<=c).
// Grid (NH, 16), 512 thr = 8 waves. Block = head a + c-tile PAIR (jt, 31-jt):
// exactly 33 C-tile steps per block -> identical work, no dispatch assumptions.
// Waves: strip = wave>>1 (16-row c-strip of the 64-row tile), parity = wave&1
// (even/odd 16-col C-chunks) -> 2-way LDS combine per phase.
// Per step: whole block double-buffer-stages Q-tile[64C][64h] + Vt-tile
// [64h][64C] f16 via XOR-source-swizzled global_load_lds (1 gll16 x2 per
// thread), one barrier per step; compute consumes LDS.
// T = MFMA(A=Q-frag,B=K-frag) = S^T; per-lane C/D layout == A-frag layout of
// mfma 16x16x16 f16 -> exp(T) feeds PV directly. No max-subtraction
// (|s| <= ~8 sigma). Rowsum via ones-B MFMA (C/D layout == O layout).
// ---------------------------------------------------------------------------
__global__ __launch_bounds__(512) void attn_mfma(
    const __half* __restrict__ Qh, const __half* __restrict__ Kh,
    const __half* __restrict__ Vt, __bf16* __restrict__ Z)
{
    __shared__ __align__(16) _Float16 Qs[2][64][64];  // 16 KB
    __shared__ __align__(16) _Float16 Vs[2][64][64];  // 16 KB
    __shared__ float smc[4][64][20];                  // 20 KB combine

    const int a    = blockIdx.x;
    const int jp   = blockIdx.y;           // 0..15
    const int t    = threadIdx.x;
    const int wave = t >> 6;
    const int lane = t & 63;
    const int strip  = wave >> 1;          // 0..3
    const int parity = wave & 1;
    const int il = lane & 15, q4 = lane >> 4;

    const int jtA = jp, jtB = 31 - jp;
    const int SA  = jtA + 1;
    const int total = 33;                  // SA + jtB + 1

    const __half* Qg = Qh + (long)a * SEQ * DH;
    const __half* Vg = Vt + (long)a * DH * SEQ;

    int c0t = jtA * 64;
    const __half* kp = Kh + ((long)a*SEQ + c0t + strip*16 + il)*DH + q4*8;
    half8 kf0 = *(const half8*)kp;
    half8 kf1 = *(const half8*)(kp + 32);

    f16x4 ones;
    #pragma unroll
    for (int j = 0; j < 4; ++j) ones[j] = (_Float16)1.0f;

    f32x4 o[4];
    #pragma unroll
    for (int ht = 0; ht < 4; ++ht) o[ht] = (f32x4){0.f,0.f,0.f,0.f};
    f32x4 lacc = {0.f,0.f,0.f,0.f};

    auto STAGE = [&](int s, int buf) {
        const int nn0 = (s < SA) ? s * 64 : (s - SA) * 64;
        {   // Q tile: 512 slots, thread t -> slot t
            int row = t >> 3, ch = (t & 7) ^ (row & 7);
            gll16((_Float16*)Qs[buf] + (long)t * 8,
                  Qg + (long)(nn0 + row) * DH + ch * 8);
        }
        {   // V^T tile
            int row = t >> 3, ch = (t & 7) ^ (row & 7);
            gll16((_Float16*)Vs[buf] + (long)t * 8,
                  Vg + (long)row * SEQ + nn0 + ch * 8);
        }
    };

    STAGE(0, 0);
    for (int s = 0; s < total; ++s) {
        __syncthreads();                       // buf[s&1] staged (vmcnt drain)
        if (s + 1 < total) STAGE(s + 1, (s + 1) & 1);
        const int  buf  = s & 1;
        const bool diag = (s == SA - 1) || (s == total - 1);

        #pragma unroll
        for (int ci = 0; ci < 2; ++ci) {
            const int cc = parity + ci * 2;
            if (diag && cc > strip) break;     // wave-uniform
            const int qrow = cc*16 + il;
            const _Float16* qsr = &Qs[buf][qrow][0];
            half8 qa = *(const half8*)(qsr + ((( q4    ) ^ (qrow & 7)) << 3));
            half8 qb = *(const half8*)(qsr + (((q4 + 4) ^ (qrow & 7)) << 3));
            f32x4 T = {0.f,0.f,0.f,0.f};
            T = MFMA_F16_K32(qa, kf0, T);
            T = MFMA_F16_K32(qb, kf1, T);
            if (diag && cc == strip) {         // mask C > c within chunk
                #pragma unroll
                for (int r = 0; r < 4; ++r)
                    if (q4*4 + r > il) T[r] = -1e30f;
            }
            f16x4 pf;
            #pragma unroll
            for (int r = 0; r < 4; ++r) pf[r] = (_Float16)__expf(T[r]);
            lacc = MFMA_F16_K16(pf, ones, lacc);
            #pragma unroll
            for (int ht = 0; ht < 4; ++ht) {
                const int vrow = ht*16 + il;
                const int vch  = (2*cc + (q4 >> 1)) ^ (vrow & 7);
                f16x4 vf = *(const f16x4*)(&Vs[buf][vrow][0] +
                                           (vch << 3) + ((q4 & 1) << 2));
                o[ht] = MFMA_F16_K16(pf, vf, o[ht]);
            }
        }

        if (diag) {                            // end of phase: combine + write
            __syncthreads();
            if (parity) {
                float* p = &smc[strip][lane][0];
                #pragma unroll
                for (int ht = 0; ht < 4; ++ht) *(f32x4*)(p + ht*4) = o[ht];
                *(f32x4*)(p + 16) = lacc;
            }
            __syncthreads();
            if (!parity) {
                const float* p = &smc[strip][lane][0];
                #pragma unroll
                for (int ht = 0; ht < 4; ++ht)
                    o[ht] += *(const f32x4*)(p + ht*4);
                lacc += *(const f32x4*)(p + 16);
                float inv[4];
                #pragma unroll
                for (int r = 0; r < 4; ++r) inv[r] = 1.0f / lacc[r];
                #pragma unroll
                for (int ht = 0; ht < 4; ++ht)
                    #pragma unroll
                    for (int r = 0; r < 4; ++r) {
                        long row = c0t + strip*16 + q4*4 + r;
                        Z[row * DE + a*64 + ht*16 + il] =
                            (__bf16)(o[ht][r] * inv[r]);
                    }
            }
            #pragma unroll
            for (int ht = 0; ht < 4; ++ht) o[ht] = (f32x4){0.f,0.f,0.f,0.f};
            lacc = (f32x4){0.f,0.f,0.f,0.f};
            if (s == SA - 1 && s != total - 1) {   // load phase-B K-frags
                c0t = jtB * 64;
                const __half* kp2 = Kh + ((long)a*SEQ + c0t + strip*16 + il)*DH + q4*8;
                kf0 = *(const half8*)kp2;
                kf1 = *(const half8*)(kp2 + 32);
            }
        }
    }
}

// ---------------------------------------------------------------------------
extern "C" void kernel_launch(void* const* d_in, const int* in_sizes, int n_in,
                              void* d_out, int out_size, void* d_ws, size_t ws_size,
                              hipStream_t stream)
{
    const float* x  = (const float*)d_in[0];
    const float* Wq = (const float*)d_in[1];
    const float* Wk = (const float*)d_in[2];
    const float* Wv = (const float*)d_in[3];
    const float* Wo = (const float*)d_in[4];
    float* out = (float*)d_out;

    const long M1 = 1024 * 1024;
    __bf16* wsb  = (__bf16*)d_ws;              // 14M 2B elems = 28 MB
    __bf16* xb   = wsb;                        // [c][e]        2M bf16
    __bf16* wqb  = wsb + 2*M1;                 // [a*64+h][e]   1M bf16
    __bf16* wkb  = wsb + 3*M1;                 // (pre-scaled 0.125)
    __bf16* wvb  = wsb + 4*M1;
    __bf16* wotb = wsb + 5*M1;                 // [e][a*64+h]   1M bf16
    __half* qkh  = (__half*)(wsb + 6*M1);      // q then k: [a][c][h] f16, 4M
    __half* vth  = (__half*)(wsb + 10*M1);     // [a][h][c] f16  2M
    __bf16* zb   = wsb + 12*M1;                // [c][a*64+h] bf16 2M
    (void)wkb; (void)wvb;

    conv_all<<<3072, 256, 0, stream>>>(x, Wq, Wk, Wv, Wo,
                                       xb, wqb, wkb, wvb, wotb);

    // fused QKV: B = [wq|wk|wv] (3072 x 1024) -> q/k f16 + v^T f16
    gemm_t<128,128,0><<<dim3(24, 16), 256, 0, stream>>>(xb, wqb, qkh, vth, nullptr);

    attn_mfma<<<dim3(NH, 16), 512, 0, stream>>>(qkh, qkh + 2*M1, vth, zb);

    // output projection: out = Z . WoT^T (f32 out)
    gemm_t<64,128,1><<<dim3(8, 32), 256, 0, stream>>>(zb, wotb, nullptr, nullptr, out);
}